// Round 20
// baseline (183.137 us; speedup 1.0000x reference)
//
#include <hip/hip_runtime.h>
#include <hip/hip_bf16.h>
#include <math.h>

#define B_N 4096
#define M_N 128
#define F_N 32
#define H_N 512
#define NFM 4096   // F*M

// wave-local LDS sync: all lanes of a wave run in lockstep, so a waitcnt on
// outstanding LDS ops makes prior cross-lane LDS writes visible to reads.
#define WAVE_SYNC() do { \
  asm volatile("s_waitcnt lgkmcnt(0)" ::: "memory"); \
  __builtin_amdgcn_sched_barrier(0); \
} while (0)

// ---------------------------------------------------------------------------
// k_pre: FUSED k_w2t + k1 — independent work, one launch.
//   blocks 0..511   : W2 transpose (k = blockIdx.x).
//   blocks 512..2559: k1, TWO samples per block, 4 cols/thread via float4.
// k1 arithmetic BIT-IDENTICAL (ascending-j scalar chains per column).
// ---------------------------------------------------------------------------
__global__ __launch_bounds__(256) void k_pre(
    const float* __restrict__ n, const float* __restrict__ W1,
    const float* __restrict__ b1, const float* __restrict__ W2,
    float* __restrict__ W2t, float* __restrict__ h_ws,
    unsigned int* __restrict__ mask)
{
  __shared__ float s_buf[32 * 132];          // w2t transpose tile
  __shared__ int s_idx[2][F_N];
  __shared__ int s_cnt0[2];

  const int t = threadIdx.x;

  if (blockIdx.x < 512) {
    // ---- W2 transpose: W2t[c][k][ig] = W2[k][ig*128+c] ----
    const int k = blockIdx.x;
    #pragma unroll
    for (int i = 0; i < 4; ++i) {
      int m0 = i * 1024 + t * 4;             // never crosses a 128 boundary
      float4 v = *(const float4*)&W2[(size_t)k * NFM + m0];
      int ig = m0 >> 7, c = m0 & 127;
      s_buf[ig * 132 + c + 0] = v.x;
      s_buf[ig * 132 + c + 1] = v.y;
      s_buf[ig * 132 + c + 2] = v.z;
      s_buf[ig * 132 + c + 3] = v.w;
    }
    __syncthreads();
    const int c  = t >> 1;
    const int ih = (t & 1) * 16;
    float* outp = W2t + (size_t)c * (H_N * F_N) + k * F_N + ih;
    #pragma unroll
    for (int i = 0; i < 4; ++i) {
      int ig = ih + i * 4;
      float4 v = make_float4(s_buf[(ig+0)*132 + c], s_buf[(ig+1)*132 + c],
                             s_buf[(ig+2)*132 + c], s_buf[(ig+3)*132 + c]);
      *(float4*)(outp + i * 4) = v;
    }
    return;
  }

  // ---- k1: two samples per block ----
  const int half = t >> 7;                   // 0: sample A, 1: sample B
  const int tl   = t & 127;                  // orbital / col-group index
  const int b    = (blockIdx.x - 512) * 2 + half;
  const int lane = t & 63;

  {
    float v = n[(size_t)b * M_N + tl];
    bool p = v > 0.5f;
    unsigned long long m = __ballot(p);      // wave = one 64-orbital half
    int before = __popcll(m & ((1ull << lane) - 1ull));
    if (lane == 0) {
      int w2 = (tl < 64) ? 0 : 2;
      mask[b*4 + w2 + 0] = (unsigned)m;
      mask[b*4 + w2 + 1] = (unsigned)(m >> 32);
    }
    if (tl < 64) {
      if (lane == 0) s_cnt0[half] = __popcll(m);
      if (p) s_idx[half][before] = tl;       // ascending within low half
    }
    __syncthreads();
    if (tl >= 64 && p) s_idx[half][s_cnt0[half] + before] = tl;
    __syncthreads();
  }

  const int c0 = tl * 4;                     // 4 consecutive cols
  float4 acc = make_float4(0.f, 0.f, 0.f, 0.f);
  #pragma unroll
  for (int j = 0; j < F_N; ++j) {
    float4 wv = *(const float4*)&W1[(size_t)s_idx[half][j] * H_N + c0];
    acc.x += wv.x; acc.y += wv.y; acc.z += wv.z; acc.w += wv.w;
  }
  float4 bv = *(const float4*)&b1[c0];       // b1 = zeros: exact
  acc.x = tanhf(acc.x + bv.x);
  acc.y = tanhf(acc.y + bv.y);
  acc.z = tanhf(acc.z + bv.z);
  acc.w = tanhf(acc.w + bv.w);
  *(float4*)&h_ws[(size_t)b * H_N + c0] = acc;
}

// ---------------------------------------------------------------------------
// k_fill (512 threads, 8 chunks/pass):
// Pass 1: per-(chunk,wave) ballot counts (8 chunks x 8 waves); wave-reduced
//   totals give cnt_c and boff_c = sum_b rank_b(c); thread 0 exclusive-
//   prefixes s_wcnt into s_pre. Pass 2: zero barriers — positions =
//   s_pre[ch*8+w] + lane rank. Entry order (ch, w, lane) = ascending b.
//   bent[c*B_N + pos] = (b<<5) | j ;  loc[b*32 + j] = boff_c + pos
// ---------------------------------------------------------------------------
__global__ __launch_bounds__(512) void k_fill(
    const unsigned int* __restrict__ mask,
    int* __restrict__ bcnt, int* __restrict__ boff,
    int* __restrict__ bent, int* __restrict__ loc)
{
  const int c = blockIdx.x;
  const int t = threadIdx.x;                 // 0..511
  const int w = t >> 6, lane = t & 63;       // 8 waves
  const int word = c >> 5, bit = c & 31;
  __shared__ int s_wcnt[64];                 // 8 chunks x 8 waves
  __shared__ int s_pre[64];
  __shared__ int s_red[16];

  // ---- pass 1: counts ----
  int cnt_loc = 0, off_loc = 0;
  #pragma unroll 1
  for (int ch = 0; ch < 8; ++ch) {
    const int b = ch * 512 + t;
    unsigned m0 = mask[(size_t)b*4+0], m1 = mask[(size_t)b*4+1];
    unsigned m2 = mask[(size_t)b*4+2], m3 = mask[(size_t)b*4+3];
    unsigned wv = (word == 0) ? m0 : (word == 1) ? m1 : (word == 2) ? m2 : m3;
    bool p = (wv >> bit) & 1u;
    int r = __popc(wv & ((1u << bit) - 1u));
    if (word > 0) r += __popc(m0);
    if (word > 1) r += __popc(m1);
    if (word > 2) r += __popc(m2);
    unsigned long long bal = __ballot(p);
    if (lane == 0) s_wcnt[ch * 8 + w] = __popcll(bal);
    cnt_loc += (int)p;
    off_loc += r;
  }
  #pragma unroll
  for (int off = 32; off > 0; off >>= 1) {
    cnt_loc += __shfl_down(cnt_loc, off);
    off_loc += __shfl_down(off_loc, off);
  }
  if (lane == 0) { s_red[w] = cnt_loc; s_red[8 + w] = off_loc; }
  __syncthreads();                           // barrier 1
  int cnt_tot = 0, off_tot = 0;
  #pragma unroll
  for (int i = 0; i < 8; ++i) { cnt_tot += s_red[i]; off_tot += s_red[8 + i]; }
  if (t == 0) {
    bcnt[c] = cnt_tot; boff[c] = off_tot;
    int run = 0;
    #pragma unroll
    for (int i = 0; i < 64; ++i) { s_pre[i] = run; run += s_wcnt[i]; }
  }
  __syncthreads();                           // barrier 2

  // ---- pass 2: fill (ascending b), no barriers ----
  #pragma unroll 1
  for (int ch = 0; ch < 8; ++ch) {
    const int b = ch * 512 + t;
    unsigned m0 = mask[(size_t)b*4+0], m1 = mask[(size_t)b*4+1];
    unsigned m2 = mask[(size_t)b*4+2], m3 = mask[(size_t)b*4+3];
    unsigned wv = (word == 0) ? m0 : (word == 1) ? m1 : (word == 2) ? m2 : m3;
    bool p = (wv >> bit) & 1u;
    int j = __popc(wv & ((1u << bit) - 1u));
    if (word > 0) j += __popc(m0);
    if (word > 1) j += __popc(m1);
    if (word > 2) j += __popc(m2);
    unsigned long long bal = __ballot(p);
    int before = __popcll(bal & ((1ull << lane) - 1ull));
    if (p) {
      int pos = s_pre[ch * 8 + w] + before;  // bucket-local, ascending b
      bent[(size_t)c * B_N + pos] = (b << 5) | j;
      loc[b * 32 + j] = off_tot + pos;
    }
  }
}

// ---------------------------------------------------------------------------
// Kernel 2 (ROUND 31): staged bucketed GEMM, ONE-WAVE BLOCKS — ZERO BARRIERS.
// r19 post-mortem: 2-wave blocks with 8 nominal blocks/CU only reached
//   occupancy 16% / VALUBusy 39%; time x VALUBusy pinned ~36 us. The
//   residual stall is the cross-wave barrier per k-tile. k3's lesson
//   transfers: a ONE-WAVE block needs no __syncthreads — WAVE_SYNC
//   (wave-local lgkm drain, ~tens of cycles) suffices for the LDS
//   double-buffer, and every wave runs fully decoupled.
// Config: 64 threads (1 wave), 64-row x 32-col tile, 8x4 micro-tile, BK=8,
//   double-buffered LDS (At[8][68]=544 + Bt[8][32]=256 -> 800 floats/buf,
//   6400 B), 64 k-tiles. Stage rows == compute rows (rbA = tyr*8, rowb
//   reused). VGPR ~95 (acc 32 + aReg 8 + bReg 4 + misc) -> 4 waves/SIMD
//   bracket; ~2048 live blocks = 8 decoupled waves/CU. r11's BK=8 penalty
//   was cross-wave barrier frequency — here barrier cost ~ 0.
// ARITHMETIC BIT-IDENTICAL: each output = one ascending-k fmaf chain
//   (t 0..63 ascending, kk 0..7 ascending, single accumulator); epilogue
//   Phi + (acc + b2) unchanged. absmax must stay exactly 0.203125.
// ---------------------------------------------------------------------------
__global__ __launch_bounds__(64) void k2_gemm_gather(
    const float* __restrict__ h, const float* __restrict__ W2t,
    const float* __restrict__ b2, const float* __restrict__ Phi,
    const int* __restrict__ bcnt, const int* __restrict__ boff,
    const int* __restrict__ bent, float* __restrict__ phi_bucket)
{
  // per buffer: At [8][68] = 544 floats + Bt [8][32] = 256 -> 800
  __shared__ __align__(16) float smem[2 * 800];    // 6400 B
  __shared__ int s_b[64];

  const int lane = threadIdx.x;              // 0..63 (one wave)
  const int c    = blockIdx.x;               // orbital 0..127
  const int cnt  = bcnt[c];
  const int t0   = blockIdx.y * 64;          // row-tile base within bucket
  if (t0 >= cnt) return;                     // block-uniform early exit
  const int base = boff[c];
  const float* w2tc = W2t + (size_t)c * (H_N * F_N);

  {
    int ii = t0 + lane;
    int e  = bent[(size_t)c * B_N + (ii < cnt ? ii : cnt - 1)];  // cnt >= 1
    s_b[lane] = e >> 5;
  }
  WAVE_SYNC();

  const int kA  = lane & 7;                  // A stage: kk (0..7)
  const int tyr = lane >> 3;                 // row group 0..7: rows tyr*8..+7
  const int tx  = lane & 7;                  // col group: igs tx*4..+3
  const int r8  = tyr * 8;                   // stage row base == compute rows

  int rowb[8];
  #pragma unroll
  for (int i = 0; i < 8; ++i) rowb[i] = s_b[r8 + i];

  float acc[8][4];
  #pragma unroll
  for (int i = 0; i < 8; ++i)
    #pragma unroll
    for (int u = 0; u < 4; ++u) acc[i][u] = 0.f;

  float aReg[8], bReg0, bReg1, bReg2, bReg3;

  // ---- prologue: stage k-tile 0 into buf0 ----
  #pragma unroll
  for (int i = 0; i < 8; ++i)
    aReg[i] = h[(size_t)rowb[i] * H_N + kA];
  bReg0 = w2tc[lane];                        // Bt[8][32]: 4 floats/lane
  bReg1 = w2tc[64 + lane];
  bReg2 = w2tc[128 + lane];
  bReg3 = w2tc[192 + lane];
  *(float4*)&smem[kA * 68 + r8] =
      make_float4(aReg[0], aReg[1], aReg[2], aReg[3]);
  *(float4*)&smem[kA * 68 + r8 + 4] =
      make_float4(aReg[4], aReg[5], aReg[6], aReg[7]);
  smem[544 + lane]       = bReg0;
  smem[544 + 64 + lane]  = bReg1;
  smem[544 + 128 + lane] = bReg2;
  smem[544 + 192 + lane] = bReg3;
  WAVE_SYNC();

  #pragma unroll 1
  for (int t = 0; t < 64; ++t) {
    float* Atc = smem + (t & 1) * 800;
    float* Btc = Atc + 544;
    float* Atn = smem + ((t + 1) & 1) * 800;
    float* Btn = Atn + 544;

    // issue next tile's global loads (latency hides under compute)
    if (t < 63) {
      int k0n = (t + 1) * 8;
      #pragma unroll
      for (int i = 0; i < 8; ++i)
        aReg[i] = h[(size_t)rowb[i] * H_N + k0n + kA];
      bReg0 = w2tc[k0n * 32 + lane];
      bReg1 = w2tc[k0n * 32 + 64 + lane];
      bReg2 = w2tc[k0n * 32 + 128 + lane];
      bReg3 = w2tc[k0n * 32 + 192 + lane];
    }

    // compute tile t: 3 x ds_read_b128 + 32 fmaf per kk
    #pragma unroll
    for (int kk = 0; kk < 8; ++kk) {
      float4 a0 = *(const float4*)&Atc[kk * 68 + r8];
      float4 a1 = *(const float4*)&Atc[kk * 68 + r8 + 4];
      float4 bv = *(const float4*)&Btc[kk * 32 + tx * 4];
      float a8[8] = {a0.x, a0.y, a0.z, a0.w, a1.x, a1.y, a1.z, a1.w};
      float b4[4] = {bv.x, bv.y, bv.z, bv.w};
      #pragma unroll
      for (int i = 0; i < 8; ++i)
        #pragma unroll
        for (int u = 0; u < 4; ++u)
          acc[i][u] = fmaf(a8[i], b4[u], acc[i][u]);
    }

    // stage tile t+1 into the idle buffer; wave-local sync flips
    if (t < 63) {
      *(float4*)&Atn[kA * 68 + r8] =
          make_float4(aReg[0], aReg[1], aReg[2], aReg[3]);
      *(float4*)&Atn[kA * 68 + r8 + 4] =
          make_float4(aReg[4], aReg[5], aReg[6], aReg[7]);
      Btn[lane]       = bReg0;
      Btn[64 + lane]  = bReg1;
      Btn[128 + lane] = bReg2;
      Btn[192 + lane] = bReg3;
      WAVE_SYNC();
    }
  }

  // ---- epilogue: coalesced float4 writes into bucket-major phi ----
  float ph[4], bb[4];
  #pragma unroll
  for (int u = 0; u < 4; ++u) {
    int colw = (tx * 4 + u) * M_N + c;
    ph[u] = Phi[colw];
    bb[u] = b2[colw];
  }
  #pragma unroll
  for (int i = 0; i < 8; ++i) {
    int r = r8 + i;
    if (t0 + r < cnt) {
      int col = base + t0 + r;               // global column index
      float v0 = ph[0] + (acc[i][0] + bb[0]);
      float v1 = ph[1] + (acc[i][1] + bb[1]);
      float v2 = ph[2] + (acc[i][2] + bb[2]);
      float v3 = ph[3] + (acc[i][3] + bb[3]);
      *(float4*)&phi_bucket[(size_t)col * 32 + tx * 4] =
          make_float4(v0, v1, v2, v3);
    }
  }
}

// ---------------------------------------------------------------------------
// Kernel 3 (r18 version): batched 32x32 fp32 LU, LAPACK sgetf2 sequence.
//  (a) 5-step isamax (column k mirrored into both 32-lane halves);
//  (c) post-swap WAVE_SYNC only when p != k.
// Separate scale pass and half-split rank-1 update (bit-identical).
// Loads columns from bucket-major phi_bucket via loc (contiguous 128 B).
// PLANAR complex output: out[0..B-1] = log|det|, out[B..2B-1] = arg(sign)
// ---------------------------------------------------------------------------
__global__ __launch_bounds__(256) void k3_det(
    const float* __restrict__ phi_bucket, const int* __restrict__ loc,
    float* __restrict__ out)
{
  __shared__ float A[4][32 * 33];
  const int w = threadIdx.x >> 6;
  const int lane = threadIdx.x & 63;
  const int b = blockIdx.x * 4 + w;
  float* Aw = A[w];

  {
    const int jj = lane & 31;
    const int hi = lane >> 5;              // 0 or 1: ig halves
    int lcol = loc[b * 32 + jj];
    const float* colp = phi_bucket + (size_t)lcol * 32 + hi * 16;
    #pragma unroll
    for (int i = 0; i < 4; ++i) {
      float4 v = *(const float4*)(colp + i * 4);
      int ig = hi * 16 + i * 4;
      Aw[(ig + 0) * 33 + jj] = v.x;
      Aw[(ig + 1) * 33 + jj] = v.y;
      Aw[(ig + 2) * 33 + jj] = v.z;
      Aw[(ig + 3) * 33 + jj] = v.w;
    }
  }
  WAVE_SYNC();

  float logabs = 0.f;
  int negs = 0;
  for (int k = 0; k < 32; ++k) {
    // (a) isamax over rows k..31 of column k (ties -> first index), 5-step
    // butterfly within each 32-lane half (both halves identical data)
    const int row = lane & 31;
    float v = -1.f;
    int vi = row;
    if (row >= k) v = fabsf(Aw[row * 33 + k]);
    #pragma unroll
    for (int off = 16; off > 0; off >>= 1) {
      float ov = __shfl_xor(v, off);
      int oi = __shfl_xor(vi, off);
      if (ov > v || (ov == v && oi < vi)) { v = ov; vi = oi; }
    }
    int p = vi;                          // uniform across the wave
    if (p != k) {
      negs ^= 1;
      if (lane < 32) {
        float tmp = Aw[k * 33 + lane];
        Aw[k * 33 + lane] = Aw[p * 33 + lane];
        Aw[p * 33 + lane] = tmp;
      }
      WAVE_SYNC();                       // (c) only when something was written
    }
    float piv = Aw[k * 33 + k];
    if (piv < 0.f) negs ^= 1;
    logabs += logf(fabsf(piv));
    if (lane > k && lane < 32) {
      float l = Aw[lane * 33 + k];
      if (fabsf(piv) >= 1.17549435e-38f) l = l * (1.0f / piv);  // sscal path
      else                               l = l / piv;           // tiny pivot
      Aw[lane * 33 + k] = l;
    }
    WAVE_SYNC();
    {
      const int mid = (k + 33) >> 1;         // balanced split of k+1..31
      const int j   = lane & 31;
      const int ilo = (lane < 32) ? (k + 1) : mid;
      const int ihi = (lane < 32) ? mid : 32;
      if (j > k) {
        float nukj = -Aw[k * 33 + j];
        for (int i = ilo; i < ihi; ++i)
          Aw[i * 33 + j] = fmaf(nukj, Aw[i * 33 + k], Aw[i * 33 + j]);
      }
    }
    WAVE_SYNC();
  }

  if (lane == 0) {
    out[b]       = logabs;                                   // Re: log|det|
    out[B_N + b] = (negs & 1) ? 3.14159265358979f : 0.0f;    // Im: arg(sign)
  }
}

// ---------------------------------------------------------------------------
extern "C" void kernel_launch(void* const* d_in, const int* in_sizes, int n_in,
                              void* d_out, int out_size, void* d_ws, size_t ws_size,
                              hipStream_t stream) {
  const float* n   = (const float*)d_in[0];
  const float* Phi = (const float*)d_in[1];
  const float* W1  = (const float*)d_in[2];
  const float* b1  = (const float*)d_in[3];
  const float* W2  = (const float*)d_in[4];
  const float* b2  = (const float*)d_in[5];
  float* out = (float*)d_out;

  char* ws = (char*)d_ws;
  float*        h_ws       = (float*)ws;                                  // 8 MB
  float*        phi_bucket = (float*)(ws + (size_t)8  * 1024 * 1024);     // 16 MB
  float*        W2t        = (float*)(ws + (size_t)24 * 1024 * 1024);     // 8 MB
  unsigned int* mask       = (unsigned int*)(ws + (size_t)32 * 1024 * 1024); // 64 KB
  int*          bent       = (int*)(ws + (size_t)32 * 1024 * 1024 + 65536);  // 2 MB
  int*          loc        = (int*)(ws + (size_t)34 * 1024 * 1024 + 65536);  // 512 KB
  int*          bcnt       = (int*)(ws + (size_t)34 * 1024 * 1024 + 65536 + 524288);
  int*          boff       = (int*)(ws + (size_t)34 * 1024 * 1024 + 65536 + 524288 + 4096);

  hipLaunchKernelGGL(k_pre, dim3(512 + B_N / 2), dim3(256), 0, stream,
                     n, W1, b1, W2, W2t, h_ws, mask);
  hipLaunchKernelGGL(k_fill, dim3(M_N), dim3(512), 0, stream,
                     mask, bcnt, boff, bent, loc);
  hipLaunchKernelGGL(k2_gemm_gather, dim3(M_N, 64), dim3(64), 0, stream,
                     h_ws, W2t, b2, Phi, bcnt, boff, bent, phi_bucket);
  hipLaunchKernelGGL(k3_det, dim3(B_N / 4), dim3(256), 0, stream,
                     phi_bucket, loc, out);
}

// Round 21
// 166.267 us; speedup vs baseline: 1.1015x; 1.1015x over previous
//
#include <hip/hip_runtime.h>
#include <hip/hip_bf16.h>
#include <math.h>

#define B_N 4096
#define M_N 128
#define F_N 32
#define H_N 512
#define NFM 4096   // F*M

// wave-local LDS sync: all lanes of a wave run in lockstep, so a waitcnt on
// outstanding LDS ops makes prior cross-lane LDS writes visible to reads.
#define WAVE_SYNC() do { \
  asm volatile("s_waitcnt lgkmcnt(0)" ::: "memory"); \
  __builtin_amdgcn_sched_barrier(0); \
} while (0)

// ---------------------------------------------------------------------------
// k_pre: FUSED k_w2t + k1 — independent work, one launch.
//   blocks 0..511   : W2 transpose (k = blockIdx.x).
//   blocks 512..2559: k1, TWO samples per block, 4 cols/thread via float4.
// k1 arithmetic BIT-IDENTICAL (ascending-j scalar chains per column).
// ---------------------------------------------------------------------------
__global__ __launch_bounds__(256) void k_pre(
    const float* __restrict__ n, const float* __restrict__ W1,
    const float* __restrict__ b1, const float* __restrict__ W2,
    float* __restrict__ W2t, float* __restrict__ h_ws,
    unsigned int* __restrict__ mask)
{
  __shared__ float s_buf[32 * 132];          // w2t transpose tile
  __shared__ int s_idx[2][F_N];
  __shared__ int s_cnt0[2];

  const int t = threadIdx.x;

  if (blockIdx.x < 512) {
    // ---- W2 transpose: W2t[c][k][ig] = W2[k][ig*128+c] ----
    const int k = blockIdx.x;
    #pragma unroll
    for (int i = 0; i < 4; ++i) {
      int m0 = i * 1024 + t * 4;             // never crosses a 128 boundary
      float4 v = *(const float4*)&W2[(size_t)k * NFM + m0];
      int ig = m0 >> 7, c = m0 & 127;
      s_buf[ig * 132 + c + 0] = v.x;
      s_buf[ig * 132 + c + 1] = v.y;
      s_buf[ig * 132 + c + 2] = v.z;
      s_buf[ig * 132 + c + 3] = v.w;
    }
    __syncthreads();
    const int c  = t >> 1;
    const int ih = (t & 1) * 16;
    float* outp = W2t + (size_t)c * (H_N * F_N) + k * F_N + ih;
    #pragma unroll
    for (int i = 0; i < 4; ++i) {
      int ig = ih + i * 4;
      float4 v = make_float4(s_buf[(ig+0)*132 + c], s_buf[(ig+1)*132 + c],
                             s_buf[(ig+2)*132 + c], s_buf[(ig+3)*132 + c]);
      *(float4*)(outp + i * 4) = v;
    }
    return;
  }

  // ---- k1: two samples per block ----
  const int half = t >> 7;                   // 0: sample A, 1: sample B
  const int tl   = t & 127;                  // orbital / col-group index
  const int b    = (blockIdx.x - 512) * 2 + half;
  const int lane = t & 63;

  {
    float v = n[(size_t)b * M_N + tl];
    bool p = v > 0.5f;
    unsigned long long m = __ballot(p);      // wave = one 64-orbital half
    int before = __popcll(m & ((1ull << lane) - 1ull));
    if (lane == 0) {
      int w2 = (tl < 64) ? 0 : 2;
      mask[b*4 + w2 + 0] = (unsigned)m;
      mask[b*4 + w2 + 1] = (unsigned)(m >> 32);
    }
    if (tl < 64) {
      if (lane == 0) s_cnt0[half] = __popcll(m);
      if (p) s_idx[half][before] = tl;       // ascending within low half
    }
    __syncthreads();
    if (tl >= 64 && p) s_idx[half][s_cnt0[half] + before] = tl;
    __syncthreads();
  }

  const int c0 = tl * 4;                     // 4 consecutive cols
  float4 acc = make_float4(0.f, 0.f, 0.f, 0.f);
  #pragma unroll
  for (int j = 0; j < F_N; ++j) {
    float4 wv = *(const float4*)&W1[(size_t)s_idx[half][j] * H_N + c0];
    acc.x += wv.x; acc.y += wv.y; acc.z += wv.z; acc.w += wv.w;
  }
  float4 bv = *(const float4*)&b1[c0];       // b1 = zeros: exact
  acc.x = tanhf(acc.x + bv.x);
  acc.y = tanhf(acc.y + bv.y);
  acc.z = tanhf(acc.z + bv.z);
  acc.w = tanhf(acc.w + bv.w);
  *(float4*)&h_ws[(size_t)b * H_N + c0] = acc;
}

// ---------------------------------------------------------------------------
// k_fill (512 threads, 8 chunks/pass):
// Pass 1: per-(chunk,wave) ballot counts (8 chunks x 8 waves); wave-reduced
//   totals give cnt_c and boff_c = sum_b rank_b(c); thread 0 exclusive-
//   prefixes s_wcnt into s_pre. Pass 2: zero barriers — positions =
//   s_pre[ch*8+w] + lane rank. Entry order (ch, w, lane) = ascending b.
//   bent[c*B_N + pos] = (b<<5) | j ;  loc[b*32 + j] = boff_c + pos
// ---------------------------------------------------------------------------
__global__ __launch_bounds__(512) void k_fill(
    const unsigned int* __restrict__ mask,
    int* __restrict__ bcnt, int* __restrict__ boff,
    int* __restrict__ bent, int* __restrict__ loc)
{
  const int c = blockIdx.x;
  const int t = threadIdx.x;                 // 0..511
  const int w = t >> 6, lane = t & 63;       // 8 waves
  const int word = c >> 5, bit = c & 31;
  __shared__ int s_wcnt[64];                 // 8 chunks x 8 waves
  __shared__ int s_pre[64];
  __shared__ int s_red[16];

  // ---- pass 1: counts ----
  int cnt_loc = 0, off_loc = 0;
  #pragma unroll 1
  for (int ch = 0; ch < 8; ++ch) {
    const int b = ch * 512 + t;
    unsigned m0 = mask[(size_t)b*4+0], m1 = mask[(size_t)b*4+1];
    unsigned m2 = mask[(size_t)b*4+2], m3 = mask[(size_t)b*4+3];
    unsigned wv = (word == 0) ? m0 : (word == 1) ? m1 : (word == 2) ? m2 : m3;
    bool p = (wv >> bit) & 1u;
    int r = __popc(wv & ((1u << bit) - 1u));
    if (word > 0) r += __popc(m0);
    if (word > 1) r += __popc(m1);
    if (word > 2) r += __popc(m2);
    unsigned long long bal = __ballot(p);
    if (lane == 0) s_wcnt[ch * 8 + w] = __popcll(bal);
    cnt_loc += (int)p;
    off_loc += r;
  }
  #pragma unroll
  for (int off = 32; off > 0; off >>= 1) {
    cnt_loc += __shfl_down(cnt_loc, off);
    off_loc += __shfl_down(off_loc, off);
  }
  if (lane == 0) { s_red[w] = cnt_loc; s_red[8 + w] = off_loc; }
  __syncthreads();                           // barrier 1
  int cnt_tot = 0, off_tot = 0;
  #pragma unroll
  for (int i = 0; i < 8; ++i) { cnt_tot += s_red[i]; off_tot += s_red[8 + i]; }
  if (t == 0) {
    bcnt[c] = cnt_tot; boff[c] = off_tot;
    int run = 0;
    #pragma unroll
    for (int i = 0; i < 64; ++i) { s_pre[i] = run; run += s_wcnt[i]; }
  }
  __syncthreads();                           // barrier 2

  // ---- pass 2: fill (ascending b), no barriers ----
  #pragma unroll 1
  for (int ch = 0; ch < 8; ++ch) {
    const int b = ch * 512 + t;
    unsigned m0 = mask[(size_t)b*4+0], m1 = mask[(size_t)b*4+1];
    unsigned m2 = mask[(size_t)b*4+2], m3 = mask[(size_t)b*4+3];
    unsigned wv = (word == 0) ? m0 : (word == 1) ? m1 : (word == 2) ? m2 : m3;
    bool p = (wv >> bit) & 1u;
    int j = __popc(wv & ((1u << bit) - 1u));
    if (word > 0) j += __popc(m0);
    if (word > 1) j += __popc(m1);
    if (word > 2) j += __popc(m2);
    unsigned long long bal = __ballot(p);
    int before = __popcll(bal & ((1ull << lane) - 1ull));
    if (p) {
      int pos = s_pre[ch * 8 + w] + before;  // bucket-local, ascending b
      bent[(size_t)c * B_N + pos] = (b << 5) | j;
      loc[b * 32 + j] = off_tot + pos;
    }
  }
}

// ---------------------------------------------------------------------------
// Kernel 2 (REVERTED to ROUND-19's config — the converged family optimum).
// r20 post-mortem: 1-wave blocks with WAVE_SYNC per k-tile regressed to
//   106 us — the wave-local lgkmcnt(0)+sched_barrier drain serializes the
//   wave's OWN staging pipeline (no co-resident wave in the block to cover
//   it, and the sched_barrier defeats compiler lgkmcnt(N) scheduling).
//   __syncthreads in a 2-wave block is CHEAPER: the other wave's compute
//   covers each wave's drain. Family now fully mapped and monotone around
//   this config: waves/block 1->106, 2->93, 4->99.6; tile rows 64->93,
//   128->99.6, 256->119; SGPR/VGPR-direct staging worse.
// Config: 128 threads (2 waves), 64-row tiles, 4x4 micro-tile, BK=16
//   (32 k-tiles), double-buffered LDS At[16][68]+Bt[16][32] (12.8 KB).
// ARITHMETIC BIT-IDENTICAL: each output = one ascending-k fmaf chain
// (t 0..31 ascending, kk 0..15 ascending, single accumulator); epilogue
// Phi + (acc + b2) unchanged. absmax must stay exactly 0.203125.
// ---------------------------------------------------------------------------
__global__ __launch_bounds__(128) void k2_gemm_gather(
    const float* __restrict__ h, const float* __restrict__ W2t,
    const float* __restrict__ b2, const float* __restrict__ Phi,
    const int* __restrict__ bcnt, const int* __restrict__ boff,
    const int* __restrict__ bent, float* __restrict__ phi_bucket)
{
  // per buffer: At [16][68] = 1088 floats + Bt [16][32] = 512 -> 1600
  __shared__ __align__(16) float smem[2 * 1600];   // 12800 B
  __shared__ int s_b[64];

  const int tid = threadIdx.x;               // 0..127
  const int c   = blockIdx.x;                // orbital 0..127
  const int cnt = bcnt[c];
  const int t0  = blockIdx.y * 64;           // row-tile base within bucket
  if (t0 >= cnt) return;                     // block-uniform early exit
  const int base = boff[c];
  const float* w2tc = W2t + (size_t)c * (H_N * F_N);

  if (tid < 64) {
    int ii = t0 + tid;
    int e  = bent[(size_t)c * B_N + (ii < cnt ? ii : cnt - 1)];  // cnt >= 1
    s_b[tid] = e >> 5;
  }
  __syncthreads();

  const int kA  = tid & 15;                  // A stage: kk (0..15)
  const int rbA = (tid >> 4) * 8;            // A stage: row base (0..56)
  const int tx  = tid & 7;                   // col group: igs tx*4..+3
  const int tyr = tid >> 3;                  // row group 0..15: rows tyr*4..+3

  int rowb[8];
  #pragma unroll
  for (int i = 0; i < 8; ++i) rowb[i] = s_b[rbA + i];

  float acc[4][4];
  #pragma unroll
  for (int i = 0; i < 4; ++i)
    #pragma unroll
    for (int u = 0; u < 4; ++u) acc[i][u] = 0.f;

  float aReg[8], bReg0, bReg1, bReg2, bReg3;

  // ---- prologue: stage k-tile 0 into buf0 ----
  #pragma unroll
  for (int i = 0; i < 8; ++i)
    aReg[i] = h[(size_t)rowb[i] * H_N + kA];
  bReg0 = w2tc[tid];                         // Bt rows: 4 floats/thread
  bReg1 = w2tc[128 + tid];
  bReg2 = w2tc[256 + tid];
  bReg3 = w2tc[384 + tid];
  *(float4*)&smem[kA * 68 + rbA] =
      make_float4(aReg[0], aReg[1], aReg[2], aReg[3]);
  *(float4*)&smem[kA * 68 + rbA + 4] =
      make_float4(aReg[4], aReg[5], aReg[6], aReg[7]);
  smem[1088 + tid]       = bReg0;
  smem[1088 + 128 + tid] = bReg1;
  smem[1088 + 256 + tid] = bReg2;
  smem[1088 + 384 + tid] = bReg3;
  __syncthreads();

  #pragma unroll 1
  for (int t = 0; t < 32; ++t) {
    float* Atc = smem + (t & 1) * 1600;
    float* Btc = Atc + 1088;
    float* Atn = smem + ((t + 1) & 1) * 1600;
    float* Btn = Atn + 1088;

    // issue next tile's global loads (latency hides under compute)
    if (t < 31) {
      int k0n = (t + 1) * 16;
      #pragma unroll
      for (int i = 0; i < 8; ++i)
        aReg[i] = h[(size_t)rowb[i] * H_N + k0n + kA];
      bReg0 = w2tc[k0n * 32 + tid];
      bReg1 = w2tc[k0n * 32 + 128 + tid];
      bReg2 = w2tc[k0n * 32 + 256 + tid];
      bReg3 = w2tc[k0n * 32 + 384 + tid];
    }

    // compute tile t: 2 x ds_read_b128 + 16 fmaf per kk
    #pragma unroll
    for (int kk = 0; kk < 16; ++kk) {
      float4 av = *(const float4*)&Atc[kk * 68 + tyr * 4];
      float4 bv = *(const float4*)&Btc[kk * 32 + tx * 4];
      float a4[4] = {av.x, av.y, av.z, av.w};
      float b4[4] = {bv.x, bv.y, bv.z, bv.w};
      #pragma unroll
      for (int i = 0; i < 4; ++i)
        #pragma unroll
        for (int u = 0; u < 4; ++u)
          acc[i][u] = fmaf(a4[i], b4[u], acc[i][u]);
    }

    // stage tile t+1 into the idle buffer; single barrier flips
    if (t < 31) {
      *(float4*)&Atn[kA * 68 + rbA] =
          make_float4(aReg[0], aReg[1], aReg[2], aReg[3]);
      *(float4*)&Atn[kA * 68 + rbA + 4] =
          make_float4(aReg[4], aReg[5], aReg[6], aReg[7]);
      Btn[tid]       = bReg0;
      Btn[128 + tid] = bReg1;
      Btn[256 + tid] = bReg2;
      Btn[384 + tid] = bReg3;
      __syncthreads();
    }
  }

  // ---- epilogue: coalesced float4 writes into bucket-major phi ----
  #pragma unroll
  for (int i = 0; i < 4; ++i) {
    int r = tyr * 4 + i;
    if (t0 + r < cnt) {
      int col = base + t0 + r;               // global column index
      float v[4];
      #pragma unroll
      for (int u = 0; u < 4; ++u) {
        int ig   = tx * 4 + u;
        int colw = ig * M_N + c;
        v[u] = Phi[colw] + (acc[i][u] + b2[colw]);
      }
      *(float4*)&phi_bucket[(size_t)col * 32 + tx * 4] =
          make_float4(v[0], v[1], v[2], v[3]);
    }
  }
}

// ---------------------------------------------------------------------------
// Kernel 3 (r18 version): batched 32x32 fp32 LU, LAPACK sgetf2 sequence.
//  (a) 5-step isamax (column k mirrored into both 32-lane halves);
//  (c) post-swap WAVE_SYNC only when p != k.
// Separate scale pass and half-split rank-1 update (bit-identical).
// Loads columns from bucket-major phi_bucket via loc (contiguous 128 B).
// PLANAR complex output: out[0..B-1] = log|det|, out[B..2B-1] = arg(sign)
// ---------------------------------------------------------------------------
__global__ __launch_bounds__(256) void k3_det(
    const float* __restrict__ phi_bucket, const int* __restrict__ loc,
    float* __restrict__ out)
{
  __shared__ float A[4][32 * 33];
  const int w = threadIdx.x >> 6;
  const int lane = threadIdx.x & 63;
  const int b = blockIdx.x * 4 + w;
  float* Aw = A[w];

  {
    const int jj = lane & 31;
    const int hi = lane >> 5;              // 0 or 1: ig halves
    int lcol = loc[b * 32 + jj];
    const float* colp = phi_bucket + (size_t)lcol * 32 + hi * 16;
    #pragma unroll
    for (int i = 0; i < 4; ++i) {
      float4 v = *(const float4*)(colp + i * 4);
      int ig = hi * 16 + i * 4;
      Aw[(ig + 0) * 33 + jj] = v.x;
      Aw[(ig + 1) * 33 + jj] = v.y;
      Aw[(ig + 2) * 33 + jj] = v.z;
      Aw[(ig + 3) * 33 + jj] = v.w;
    }
  }
  WAVE_SYNC();

  float logabs = 0.f;
  int negs = 0;
  for (int k = 0; k < 32; ++k) {
    // (a) isamax over rows k..31 of column k (ties -> first index), 5-step
    // butterfly within each 32-lane half (both halves identical data)
    const int row = lane & 31;
    float v = -1.f;
    int vi = row;
    if (row >= k) v = fabsf(Aw[row * 33 + k]);
    #pragma unroll
    for (int off = 16; off > 0; off >>= 1) {
      float ov = __shfl_xor(v, off);
      int oi = __shfl_xor(vi, off);
      if (ov > v || (ov == v && oi < vi)) { v = ov; vi = oi; }
    }
    int p = vi;                          // uniform across the wave
    if (p != k) {
      negs ^= 1;
      if (lane < 32) {
        float tmp = Aw[k * 33 + lane];
        Aw[k * 33 + lane] = Aw[p * 33 + lane];
        Aw[p * 33 + lane] = tmp;
      }
      WAVE_SYNC();                       // (c) only when something was written
    }
    float piv = Aw[k * 33 + k];
    if (piv < 0.f) negs ^= 1;
    logabs += logf(fabsf(piv));
    if (lane > k && lane < 32) {
      float l = Aw[lane * 33 + k];
      if (fabsf(piv) >= 1.17549435e-38f) l = l * (1.0f / piv);  // sscal path
      else                               l = l / piv;           // tiny pivot
      Aw[lane * 33 + k] = l;
    }
    WAVE_SYNC();
    {
      const int mid = (k + 33) >> 1;         // balanced split of k+1..31
      const int j   = lane & 31;
      const int ilo = (lane < 32) ? (k + 1) : mid;
      const int ihi = (lane < 32) ? mid : 32;
      if (j > k) {
        float nukj = -Aw[k * 33 + j];
        for (int i = ilo; i < ihi; ++i)
          Aw[i * 33 + j] = fmaf(nukj, Aw[i * 33 + k], Aw[i * 33 + j]);
      }
    }
    WAVE_SYNC();
  }

  if (lane == 0) {
    out[b]       = logabs;                                   // Re: log|det|
    out[B_N + b] = (negs & 1) ? 3.14159265358979f : 0.0f;    // Im: arg(sign)
  }
}

// ---------------------------------------------------------------------------
extern "C" void kernel_launch(void* const* d_in, const int* in_sizes, int n_in,
                              void* d_out, int out_size, void* d_ws, size_t ws_size,
                              hipStream_t stream) {
  const float* n   = (const float*)d_in[0];
  const float* Phi = (const float*)d_in[1];
  const float* W1  = (const float*)d_in[2];
  const float* b1  = (const float*)d_in[3];
  const float* W2  = (const float*)d_in[4];
  const float* b2  = (const float*)d_in[5];
  float* out = (float*)d_out;

  char* ws = (char*)d_ws;
  float*        h_ws       = (float*)ws;                                  // 8 MB
  float*        phi_bucket = (float*)(ws + (size_t)8  * 1024 * 1024);     // 16 MB
  float*        W2t        = (float*)(ws + (size_t)24 * 1024 * 1024);     // 8 MB
  unsigned int* mask       = (unsigned int*)(ws + (size_t)32 * 1024 * 1024); // 64 KB
  int*          bent       = (int*)(ws + (size_t)32 * 1024 * 1024 + 65536);  // 2 MB
  int*          loc        = (int*)(ws + (size_t)34 * 1024 * 1024 + 65536);  // 512 KB
  int*          bcnt       = (int*)(ws + (size_t)34 * 1024 * 1024 + 65536 + 524288);
  int*          boff       = (int*)(ws + (size_t)34 * 1024 * 1024 + 65536 + 524288 + 4096);

  hipLaunchKernelGGL(k_pre, dim3(512 + B_N / 2), dim3(256), 0, stream,
                     n, W1, b1, W2, W2t, h_ws, mask);
  hipLaunchKernelGGL(k_fill, dim3(M_N), dim3(512), 0, stream,
                     mask, bcnt, boff, bent, loc);
  hipLaunchKernelGGL(k2_gemm_gather, dim3(M_N, 64), dim3(128), 0, stream,
                     h_ws, W2t, b2, Phi, bcnt, boff, bent, phi_bucket);
  hipLaunchKernelGGL(k3_det, dim3(B_N / 4), dim3(256), 0, stream,
                     phi_bucket, loc, out);
}